// Round 4
// baseline (51.106 us; speedup 1.0000x reference)
//
#include <hip/hip_runtime.h>

// Problem constants (from reference setup_inputs)
constexpr int B = 512;
constexpr int S = 16384;
constexpr int NTOK = B * S;                      // 8388608
constexpr int TPT = 16;                          // tokens per thread, 4x int4
constexpr int NBLOCKS = NTOK / TPT / 256;        // 2048
constexpr int NLINES = 32;                       // spread accumulator cachelines
// d_ws layout: uint acc[NLINES][16] (one 64B line each, slots 0..2 used),
//              uint ticket at byte offset NLINES*64.
constexpr int WS_ZERO_BYTES = NLINES * 64 + 64;

__global__ __launch_bounds__(256) void mpl_fused(const int* __restrict__ tokens,
                                                 unsigned int* __restrict__ ws,
                                                 float* __restrict__ out) {
    const int tid = blockIdx.x * 256 + threadIdx.x;
    const int t0 = tid * TPT;

    int toks[TPT + 1];
    const int4* p = reinterpret_cast<const int4*>(tokens + t0);
    int4 x0 = p[0], x1 = p[1], x2 = p[2], x3 = p[3];
    toks[0]  = x0.x; toks[1]  = x0.y; toks[2]  = x0.z; toks[3]  = x0.w;
    toks[4]  = x1.x; toks[5]  = x1.y; toks[6]  = x1.z; toks[7]  = x1.w;
    toks[8]  = x2.x; toks[9]  = x2.y; toks[10] = x2.z; toks[11] = x2.w;
    toks[12] = x3.x; toks[13] = x3.y; toks[14] = x3.z; toks[15] = x3.w;

    // Rows are S=16384 tokens; 16-token chunks never straddle rows. At a row
    // end, peek our own last token: the duplicated pair contributes 0 to all
    // three counters, so the pair loop needs no predication.
    const int rowEnd = ((t0 + TPT) & (S - 1)) == 0 ? 0 : 1;  // 0 at row end
    toks[TPT] = tokens[t0 + 15 + rowEnd];        // cache-hit peek

    int rc = 0, hc = 0, mc = 0;
    int qp = 0, pcp = 0, pitp = 0;
#pragma unroll
    for (int j = 0; j <= TPT; ++j) {
        const int t = toks[j];
        const int q = (t + 256) >> 9;            // ts indicator in bit 0 (t<1024)
        const int pit = (t < 128) ? t : 0;       // note-on pitch
        const int pc = pit % 12;
        if (j > 0) {
            rc += (qp ^ q) & 1;                  // time-shift transition
            const int xh = pcp - pc + 11;        // in [0,22]
            hc += (0x00420021u >> xh) & 1;       // pc diff in {-11,-6,6,11}
            const unsigned ym = (unsigned)(pitp - pit + 12);
            mc += (ym > 24u) ? 1 : 0;            // |pitch diff| > 12
        }
        qp = q; pcp = pc; pitp = pit;
    }

    // Wave(64) shuffle reduce: rc,mc packed (wave sums <= 1024 each), hc alone.
    unsigned int pk = (unsigned)rc | ((unsigned)mc << 16);
    unsigned int hh = (unsigned)hc;
#pragma unroll
    for (int off = 32; off > 0; off >>= 1) {
        pk += __shfl_down(pk, off, 64);
        hh += __shfl_down(hh, off, 64);
    }

    __shared__ unsigned int s[2][4];
    __shared__ unsigned int sLast;
    const int wave = threadIdx.x >> 6;
    if ((threadIdx.x & 63) == 0) {
        s[0][wave] = pk;
        s[1][wave] = hh;
    }
    __syncthreads();

    unsigned int* acc = ws;                       // [NLINES][16]
    unsigned int* ticket = ws + NLINES * 16;

    if (threadIdx.x == 0) {
        unsigned int pks = s[0][0] + s[0][1] + s[0][2] + s[0][3];
        unsigned int hs  = s[1][0] + s[1][1] + s[1][2] + s[1][3];
        const int line = (blockIdx.x & (NLINES - 1)) * 16;
        atomicAdd(&acc[line + 0], pks & 0xFFFFu);  // rc
        atomicAdd(&acc[line + 1], hs);             // hc
        atomicAdd(&acc[line + 2], pks >> 16);      // mc
        __threadfence();                           // data atomics before ticket
        unsigned int old = atomicAdd(ticket, 1u);
        sLast = (old == (unsigned)(NBLOCKS - 1)) ? 1u : 0u;
    }
    __syncthreads();

    if (sLast && threadIdx.x < 64) {
        unsigned int r = 0, h = 0, m = 0;
        if (threadIdx.x < NLINES) {
            const int line = threadIdx.x * 16;
            r = atomicAdd(&acc[line + 0], 0u);     // coherent device-scope reads
            h = atomicAdd(&acc[line + 1], 0u);
            m = atomicAdd(&acc[line + 2], 0u);
        }
#pragma unroll
        for (int off = 16; off > 0; off >>= 1) {
            r += __shfl_down(r, off, 64);
            h += __shfl_down(h, off, 64);
            m += __shfl_down(m, off, 64);
        }
        if (threadIdx.x == 0) {
            const double pairs = (double)B * (double)(S - 1);
            const double all = (double)B * (double)S;
            out[0] = (float)((double)r / pairs + (double)h / all + (double)m / pairs);
        }
    }
}

extern "C" void kernel_launch(void* const* d_in, const int* in_sizes, int n_in,
                              void* d_out, int out_size, void* d_ws, size_t ws_size,
                              hipStream_t stream) {
    const int* tokens = (const int*)d_in[0];
    unsigned int* ws = (unsigned int*)d_ws;

    hipMemsetAsync(ws, 0, WS_ZERO_BYTES, stream);
    mpl_fused<<<NBLOCKS, 256, 0, stream>>>(tokens, ws, (float*)d_out);
}

// Round 5
// 15.827 us; speedup vs baseline: 3.2291x; 3.2291x over previous
//
#include <hip/hip_runtime.h>

// Problem constants (from reference setup_inputs)
constexpr int B = 512;
constexpr int S = 16384;
constexpr int NTOK = B * S;                      // 8388608
constexpr int TPT = 32;                          // tokens per thread, 8x int4
constexpr int NBLOCKS = NTOK / TPT / 256;        // 1024

__global__ __launch_bounds__(256) void mpl_main(const int* __restrict__ tokens,
                                                unsigned int* __restrict__ partials) {
    const int tid = blockIdx.x * 256 + threadIdx.x;
    const int lane = threadIdx.x & 63;
    const int t0 = tid * TPT;

    int toks[TPT + 1];
    const int4* p = reinterpret_cast<const int4*>(tokens + t0);
#pragma unroll
    for (int v = 0; v < TPT / 4; ++v) {
        int4 x = p[v];
        toks[v * 4 + 0] = x.x;
        toks[v * 4 + 1] = x.y;
        toks[v * 4 + 2] = x.z;
        toks[v * 4 + 3] = x.w;
    }

    // Cross-chunk token: lane i+1's first token, via shuffle (no global load).
    // Lane 63 needs the next wave-region's first token; rows are 16384 tokens
    // = 8 wave-regions, so ONLY lane 63 can sit at a row boundary. At a row
    // end, duplicate our own last token (the pair contributes 0 everywhere).
    int nxt = __shfl(toks[0], lane + 1, 64);
    if (lane == 63) {
        const bool rowEnd = ((t0 + TPT) & (S - 1)) == 0;
        nxt = rowEnd ? toks[TPT - 1] : tokens[t0 + TPT];
    }
    toks[TPT] = nxt;

    int rc = 0, hc = 0, mc = 0;
    int qp = 0, pcp = 0, pitp = 0;
#pragma unroll
    for (int j = 0; j <= TPT; ++j) {
        const int t = toks[j];
        const int q = (t + 256) >> 9;            // ts indicator in bit 0 (t<1024)
        const int pit = (t < 128) ? t : 0;       // note-on pitch
        const int pc = pit % 12;
        if (j > 0) {
            rc += (qp ^ q) & 1;                  // time-shift transition
            const int xh = pcp - pc + 11;        // in [0,22]
            hc += (0x00420021u >> xh) & 1;       // pc diff in {-11,-6,6,11}
            const unsigned ym = (unsigned)(pitp - pit + 12);
            mc += (ym > 24u) ? 1 : 0;            // |pitch diff| > 12
        }
        qp = q; pcp = pc; pitp = pit;
    }

    // Wave(64) shuffle reduce: rc,mc packed (wave sums <= 2048 each), hc alone.
    unsigned int pk = (unsigned)rc | ((unsigned)mc << 16);
    unsigned int hh = (unsigned)hc;
#pragma unroll
    for (int off = 32; off > 0; off >>= 1) {
        pk += __shfl_down(pk, off, 64);
        hh += __shfl_down(hh, off, 64);
    }

    __shared__ unsigned int s[2][4];
    const int wave = threadIdx.x >> 6;
    if ((threadIdx.x & 63) == 0) {
        s[0][wave] = pk;
        s[1][wave] = hh;
    }
    __syncthreads();
    if (threadIdx.x == 0) {
        // Block sums: rc,mc <= 8192 each -> still fit packed 16-bit fields.
        partials[blockIdx.x]           = s[0][0] + s[0][1] + s[0][2] + s[0][3];
        partials[NBLOCKS + blockIdx.x] = s[1][0] + s[1][1] + s[1][2] + s[1][3];
    }
}

__global__ __launch_bounds__(256) void mpl_reduce(const unsigned int* __restrict__ partials,
                                                  float* __restrict__ out) {
    // partials[0..NBLOCKS): pk = rc | mc<<16 ; partials[NBLOCKS..2N): hc
    const uint4* ppk = reinterpret_cast<const uint4*>(partials);
    const uint4* phh = reinterpret_cast<const uint4*>(partials + NBLOCKS);
    unsigned int r = 0, m = 0, h = 0;
#pragma unroll 1
    for (int j = threadIdx.x; j < NBLOCKS / 4; j += 256) {  // exactly 1 iter/thread
        uint4 a = ppk[j];
        r += (a.x & 0xFFFFu) + (a.y & 0xFFFFu) + (a.z & 0xFFFFu) + (a.w & 0xFFFFu);
        m += (a.x >> 16) + (a.y >> 16) + (a.z >> 16) + (a.w >> 16);
        uint4 b = phh[j];
        h += b.x + b.y + b.z + b.w;
    }
#pragma unroll
    for (int off = 32; off > 0; off >>= 1) {
        r += __shfl_down(r, off, 64);
        m += __shfl_down(m, off, 64);
        h += __shfl_down(h, off, 64);
    }
    __shared__ unsigned int s[3][4];
    const int wave = threadIdx.x >> 6;
    if ((threadIdx.x & 63) == 0) {
        s[0][wave] = r; s[1][wave] = m; s[2][wave] = h;
    }
    __syncthreads();
    if (threadIdx.x == 0) {
        unsigned int rt = s[0][0] + s[0][1] + s[0][2] + s[0][3];
        unsigned int mt = s[1][0] + s[1][1] + s[1][2] + s[1][3];
        unsigned int ht = s[2][0] + s[2][1] + s[2][2] + s[2][3];
        const double pairs = (double)B * (double)(S - 1);
        const double all = (double)B * (double)S;
        out[0] = (float)((double)rt / pairs + (double)ht / all + (double)mt / pairs);
    }
}

extern "C" void kernel_launch(void* const* d_in, const int* in_sizes, int n_in,
                              void* d_out, int out_size, void* d_ws, size_t ws_size,
                              hipStream_t stream) {
    const int* tokens = (const int*)d_in[0];
    unsigned int* partials = (unsigned int*)d_ws;  // 2 * 1024 uints = 8 KB

    mpl_main<<<NBLOCKS, 256, 0, stream>>>(tokens, partials);
    mpl_reduce<<<1, 256, 0, stream>>>(partials, (float*)d_out);
}